// Round 7
// baseline (273.382 us; speedup 1.0000x reference)
//
#include <hip/hip_runtime.h>
#include <hip/hip_bf16.h>

// FractalTransformer fused kernels, round 7.
// vs r6: (1) T15 acc double-pipeline in fractal_attn -- update(t2-1) runs
// on VALU/trans while MFMA(t2) fills the other acc set (independent deps,
// statically unrolled 2-step so all indexing is compile-time); the update
// also hides the L2 latency of loads(t2) issued at iter top. (2) 4-wave
// blocks (grid 1024): all 4 waves read the SAME kfrag stream -> L1 serves
// ~3/4 of k-reads. Still no LDS, no barriers.

typedef __attribute__((ext_vector_type(8))) short short8;
typedef __attribute__((ext_vector_type(4))) float f32x4;
typedef __attribute__((ext_vector_type(8))) _Float16 half8;
typedef __attribute__((ext_vector_type(4))) _Float16 half4;

#define DD 256
#define SS 512
#define LOG2E 1.4426950408889634f
#define LN2   0.6931471805599453f

__device__ __forceinline__ unsigned short f2bf(float f) {
  unsigned int b = __float_as_uint(f);
  b += 0x7FFFu + ((b >> 16) & 1u);   // RNE
  return (unsigned short)(b >> 16);
}
__device__ __forceinline__ short8 cvt8(f32x4 lo, f32x4 hi) {
  short8 r;
  r[0]=(short)f2bf(lo[0]); r[1]=(short)f2bf(lo[1]);
  r[2]=(short)f2bf(lo[2]); r[3]=(short)f2bf(lo[3]);
  r[4]=(short)f2bf(hi[0]); r[5]=(short)f2bf(hi[1]);
  r[6]=(short)f2bf(hi[2]); r[7]=(short)f2bf(hi[3]);
  return r;
}

// ------------------------------------------------------------------
// One-time: bf16-convert 6 weights; (w_al + I) -> f16. out = 7 x [256][256].
// ------------------------------------------------------------------
__global__ __launch_bounds__(256) void prep_weights(
    const float* __restrict__ w0, const float* __restrict__ w1,
    const float* __restrict__ w2, const float* __restrict__ w3,
    const float* __restrict__ w4, const float* __restrict__ w5,
    const float* __restrict__ wal, unsigned short* __restrict__ out)
{
  const int bi = blockIdx.x;               // 7*32
  const int m = bi >> 5;
  const int off = ((bi & 31) * 256 + threadIdx.x) * 8;
  const float* src = m==0?w0: m==1?w1: m==2?w2: m==3?w3: m==4?w4: m==5?w5: wal;
  f32x4 a = *(const f32x4*)(src + off);
  f32x4 b = *(const f32x4*)(src + off + 4);
  if (m == 6) {                            // fold residual (+I), store f16
    const int e = off >> 8, d = off & 255;
#pragma unroll
    for (int jj = 0; jj < 4; ++jj) {
      if (e == d + jj)     a[jj] += 1.0f;
      if (e == d + 4 + jj) b[jj] += 1.0f;
    }
    half8 h;
#pragma unroll
    for (int jj = 0; jj < 4; ++jj) {
      h[jj]     = (_Float16)a[jj];
      h[jj + 4] = (_Float16)b[jj];
    }
    *(half8*)(out + (size_t)m * 65536 + off) = h;
  } else {
    *(short8*)(out + (size_t)m * 65536 + off) = cvt8(a, b);
  }
}

// ------------------------------------------------------------------
// out[1024,256] = A @ Wbf^T (+res1)(+res2). grid 256 = 64 rowblk x 4 colblk.
// ------------------------------------------------------------------
__global__ __launch_bounds__(256) void linear_bf(
    const float* __restrict__ A, const unsigned short* __restrict__ Wbf,
    const float* __restrict__ res1, const float* __restrict__ res2,
    float* __restrict__ out)
{
  const int bi = blockIdx.x;
  const int rb = (bi >> 2) * 16;
  const int cb = (bi & 3) * 64;
  const int tid = threadIdx.x;
  const int wv = tid >> 6, lane = tid & 63;
  const int g = lane >> 4, c = lane & 15;
  const int arow = rb + c;
  const int wrow = cb + wv * 16 + c;

  f32x4 acc = (f32x4){0.f, 0.f, 0.f, 0.f};
#pragma unroll
  for (int ks = 0; ks < 8; ++ks) {
    const int d0 = ks * 32 + g * 8;
    f32x4 a0 = *(const f32x4*)(A + arow * DD + d0);
    f32x4 a1 = *(const f32x4*)(A + arow * DD + d0 + 4);
    short8 av = cvt8(a0, a1);
    short8 bv = *(const short8*)(Wbf + wrow * DD + d0);
    acc = __builtin_amdgcn_mfma_f32_16x16x32_bf16(av, bv, acc, 0, 0, 0);
  }
#pragma unroll
  for (int j = 0; j < 4; ++j) {
    const int ro = rb + g * 4 + j;
    const int co = cb + wv * 16 + c;
    float v = acc[j];
    if (res1) v += res1[ro * DD + co];
    if (res2) v += res2[ro * DD + co];
    out[ro * DD + co] = v;
  }
}

// ------------------------------------------------------------------
// q = f16((X + X@Wq^T)*log2e);  k,v = f16(X + X@{Wk,Wv}^T)
// ------------------------------------------------------------------
__global__ __launch_bounds__(256) void linear_qkv(
    const float* __restrict__ X,
    const unsigned short* __restrict__ Wq, const unsigned short* __restrict__ Wk,
    const unsigned short* __restrict__ Wv,
    _Float16* __restrict__ qout, _Float16* __restrict__ kout,
    _Float16* __restrict__ vout)
{
  const int bi = blockIdx.x;
  const int rb = (bi >> 2) * 16;
  const int cb = (bi & 3) * 64;
  const int tid = threadIdx.x;
  const int wv = tid >> 6, lane = tid & 63;
  const int g = lane >> 4, c = lane & 15;
  const int arow = rb + c;
  const int wrow = cb + wv * 16 + c;

  f32x4 aq = (f32x4){0.f,0.f,0.f,0.f};
  f32x4 ak = (f32x4){0.f,0.f,0.f,0.f};
  f32x4 av_ = (f32x4){0.f,0.f,0.f,0.f};
#pragma unroll
  for (int ks = 0; ks < 8; ++ks) {
    const int d0 = ks * 32 + g * 8;
    f32x4 a0 = *(const f32x4*)(X + arow * DD + d0);
    f32x4 a1 = *(const f32x4*)(X + arow * DD + d0 + 4);
    short8 af = cvt8(a0, a1);
    short8 bq = *(const short8*)(Wq + wrow * DD + d0);
    aq = __builtin_amdgcn_mfma_f32_16x16x32_bf16(af, bq, aq, 0, 0, 0);
    short8 bk = *(const short8*)(Wk + wrow * DD + d0);
    ak = __builtin_amdgcn_mfma_f32_16x16x32_bf16(af, bk, ak, 0, 0, 0);
    short8 bv = *(const short8*)(Wv + wrow * DD + d0);
    av_ = __builtin_amdgcn_mfma_f32_16x16x32_bf16(af, bv, av_, 0, 0, 0);
  }
#pragma unroll
  for (int j = 0; j < 4; ++j) {
    const int ro = rb + g * 4 + j;
    const int co = cb + wv * 16 + c;
    const float base = X[ro * DD + co];
    qout[ro * DD + co] = (_Float16)((base + aq[j]) * LOG2E);
    kout[ro * DD + co] = (_Float16)(base + ak[j]);
    vout[ro * DD + co] = (_Float16)(base + av_[j]);
  }
}

// ------------------------------------------------------------------
// Pack k,v (f16, [b][s][d]) into MFMA-fragment order.
// k: ids [0, 32768): id = b*16384 + t2*512 + ks*64 + lane -> 8 f16:
//   k[b][t2*16 + (lane&15)][ks*32 + (lane>>4)*8 + 0..7]
// v: ids [32768, 98304): id2 = b*32768 + t2*1024 + wv*256 + i*64 + lane
//   -> 4 f16: v[b][t2*16 + (lane&15)][wv*64 + i*16 + (lane>>4)*4 + 0..3]
// ------------------------------------------------------------------
__global__ __launch_bounds__(256) void pack_kv(
    const _Float16* __restrict__ k, const _Float16* __restrict__ v,
    _Float16* __restrict__ kfrag, _Float16* __restrict__ vfrag)
{
  const int id = blockIdx.x * 256 + threadIdx.x;   // 98304
  if (id < 32768) {
    const int lane = id & 63, ks = (id >> 6) & 7, t2 = (id >> 9) & 31, b = id >> 14;
    const int g = lane >> 4, c = lane & 15;
    const _Float16* src = k + ((size_t)(b * SS + t2 * 16 + c) * DD + ks * 32 + g * 8);
    *(half8*)(kfrag + (size_t)id * 8) = *(const half8*)src;
  } else {
    const int id2 = id - 32768;                    // 0..65535
    const int lane = id2 & 63, i = (id2 >> 6) & 3, wv = (id2 >> 8) & 3,
              t2 = (id2 >> 10) & 31, b = id2 >> 15;
    const int g = lane >> 4, c = lane & 15;
    const _Float16* src = v + ((size_t)(b * SS + t2 * 16 + c) * DD + wv * 64 + i * 16 + g * 4);
    *(half4*)(vfrag + (size_t)id2 * 4) = *(const half4*)src;
  }
}

// ------------------------------------------------------------------
// Fused fractal attention v7. Grid 1024 = b x sq; 4 waves (256 thr).
// Wave wv owns e in [wv*64, +64). No LDS/barriers; all 4 waves stream the
// SAME kfrag sequence (L1-shared). T15: update(t2-1) overlaps MFMA(t2).
// ------------------------------------------------------------------
__global__ __launch_bounds__(256, 2) void fractal_attn(
    const _Float16* __restrict__ walI,   // f16 (wal+I), [256][256]
    const _Float16* __restrict__ qf,     // f16, pre-scaled by log2e
    const _Float16* __restrict__ kfrag,
    const _Float16* __restrict__ vfrag,
    float* __restrict__ vsum)
{
  const int bid = blockIdx.x;            // 1024
  const int sq = bid & 511;
  const int b  = bid >> 9;
  const int tid = threadIdx.x;
  const int wv = tid >> 6;
  const int lane = tid & 63;
  const int g = lane >> 4, c = lane & 15;

  // ---- A' fragments: wave owns e in [wv*64, wv*64+64) ----
  half8 afrag[4][8];
  {
    const _Float16* qrow = qf + (size_t)(b * SS + sq) * DD;
    half8 q8[8];
#pragma unroll
    for (int ks = 0; ks < 8; ++ks)
      q8[ks] = *(const half8*)(qrow + ks * 32 + g * 8);
#pragma unroll
    for (int i = 0; i < 4; ++i) {
      const int e = wv * 64 + i * 16 + c;
      const _Float16* wrow = walI + (size_t)e * DD;
#pragma unroll
      for (int ks = 0; ks < 8; ++ks)
        afrag[i][ks] = (*(const half8*)(wrow + ks * 32 + g * 8)) * q8[ks];
    }
  }

  // ---- fragment stream bases ----
  const _Float16* kfb = kfrag + (size_t)b * 131072 + lane * 8;   // + t2*4096 + ks*512
  const _Float16* vfb = vfrag + (size_t)b * 131072 + wv * 1024 + lane * 4;  // + t2*4096 + i*256

  // ---- state: 16 e-slots per lane (e = wv*64 + i*16 + g*4 + j) ----
  float mst[16], sst[16], vst[16];
#pragma unroll
  for (int s = 0; s < 16; ++s) { mst[s] = -1e30f; sst[s] = 0.f; vst[s] = 0.f; }

  half8 bf[8];
  half4 vqA[4], vqB[4];
  f32x4 accA[4], accB[4];
  const f32x4 zeroc = (f32x4){0.f, 0.f, 0.f, 0.f};

#define LOADK(T2)                                                   \
  {                                                                 \
    const _Float16* kf_ = kfb + (T2) * 4096;                        \
    _Pragma("unroll")                                               \
    for (int ks = 0; ks < 8; ++ks)                                  \
      bf[ks] = *(const half8*)(kf_ + ks * 512);                     \
  }
#define LOADV(T2, VQ)                                               \
  {                                                                 \
    const _Float16* vf_ = vfb + (T2) * 4096;                        \
    _Pragma("unroll")                                               \
    for (int i = 0; i < 4; ++i)                                     \
      VQ[i] = *(const half4*)(vf_ + i * 256);                       \
  }
#define MFMA_INTO(ACC)                                              \
  {                                                                 \
    __builtin_amdgcn_s_setprio(1);                                  \
    _Pragma("unroll")                                               \
    for (int i = 0; i < 4; ++i)                                     \
      ACC[i] = __builtin_amdgcn_mfma_f32_16x16x32_f16(              \
          afrag[i][0], bf[0], zeroc, 0, 0, 0);                      \
    _Pragma("unroll")                                               \
    for (int ks = 1; ks < 8; ++ks)                                  \
      _Pragma("unroll")                                             \
      for (int i = 0; i < 4; ++i)                                   \
        ACC[i] = __builtin_amdgcn_mfma_f32_16x16x32_f16(            \
            afrag[i][ks], bf[ks], ACC[i], 0, 0, 0);                 \
    __builtin_amdgcn_s_setprio(0);                                  \
  }
#define UPDATE(ACC, VQ)                                             \
  {                                                                 \
    _Pragma("unroll")                                               \
    for (int i = 0; i < 4; ++i)                                     \
      _Pragma("unroll")                                             \
      for (int j = 0; j < 4; ++j) {                                 \
        const int s = i * 4 + j;                                    \
        const float L = ACC[i][j];                                  \
        mst[s] = fmaxf(mst[s], L);                                  \
        const float p = L * __builtin_amdgcn_exp2f(L);              \
        sst[s] += fabsf(p);                                         \
        vst[s] = fmaf((float)VQ[i][j], p, vst[s]);                  \
      }                                                             \
  }

  // ---- software-pipelined main loop (even tiles -> accA, odd -> accB) ----
  LOADK(0); LOADV(0, vqA);
  MFMA_INTO(accA);
#pragma unroll 1
  for (int t2 = 1; t2 < 31; t2 += 2) {
    LOADK(t2); LOADV(t2, vqB);
    UPDATE(accA, vqA);               // tile t2-1 (even)
    MFMA_INTO(accB);                 // tile t2   (odd)
    LOADK(t2 + 1); LOADV(t2 + 1, vqA);
    UPDATE(accB, vqB);               // tile t2   (odd)
    MFMA_INTO(accA);                 // tile t2+1 (even)
  }
  LOADK(31); LOADV(31, vqB);
  UPDATE(accA, vqA);                 // tile 30
  MFMA_INTO(accB);                   // tile 31
  UPDATE(accB, vqB);                 // tile 31

#undef LOADK
#undef LOADV
#undef MFMA_INTO
#undef UPDATE

  // ---- merge across the 16 sk-lanes (same g => same e) ----
#pragma unroll
  for (int mask = 1; mask <= 8; mask <<= 1) {
#pragma unroll
    for (int s = 0; s < 16; ++s) {
      mst[s] = fmaxf(mst[s], __shfl_xor(mst[s], mask));
      sst[s] += __shfl_xor(sst[s], mask);
      vst[s] += __shfl_xor(vst[s], mask);
    }
  }

  if (c == 0) {
    float* orow = vsum + (size_t)(b * SS + sq) * DD;
#pragma unroll
    for (int i = 0; i < 4; ++i) {
      f32x4 o;
#pragma unroll
      for (int j = 0; j < 4; ++j) {
        const int s = i * 4 + j;
        const float tt = LN2 * __builtin_amdgcn_exp2f(-mst[s]);
        o[j] = vst[s] * tt / (sst[s] * tt + 1.0f);
      }
      *(f32x4*)(orow + wv * 64 + i * 16 + g * 4) = o;
    }
  }
}

// ------------------------------------------------------------------
extern "C" void kernel_launch(void* const* d_in, const int* in_sizes, int n_in,
                              void* d_out, int out_size, void* d_ws, size_t ws_size,
                              hipStream_t stream) {
  const float* x     = (const float*)d_in[0];
  const float* w_pre = (const float*)d_in[1];
  const float* w_q   = (const float*)d_in[2];
  const float* w_k   = (const float*)d_in[3];
  const float* w_va  = (const float*)d_in[4];
  const float* w_al  = (const float*)d_in[5];
  const float* w_vo  = (const float*)d_in[6];
  const float* w_end = (const float*)d_in[7];
  float* out = (float*)d_out;

  char* ws = (char*)d_ws;
  float*    X     = (float*)(ws);                         // 1MB
  float*    Y     = (float*)(ws + (1 << 20));             // 1MB
  float*    vsum  = (float*)(ws + (2 << 20));             // 1MB
  _Float16* qf16  = (_Float16*)(ws + (3 << 20));          // 512KB
  _Float16* kf16  = (_Float16*)(ws + (3 << 20) + (512 << 10));
  _Float16* vf16  = (_Float16*)(ws + (4 << 20));
  _Float16* kfrag = (_Float16*)(ws + (4 << 20) + (512 << 10));  // 512KB
  _Float16* vfrag = (_Float16*)(ws + (5 << 20));                // 512KB
  unsigned short* wbf = (unsigned short*)(ws + (5 << 20) + (512 << 10));
  // wbf order: pre, q, k, va, vo, end, walI(+I, f16)

  prep_weights<<<224, 256, 0, stream>>>(w_pre, w_q, w_k, w_va, w_vo, w_end,
                                        w_al, wbf);
  linear_bf<<<256, 256, 0, stream>>>(x, wbf + 0 * 65536, nullptr, nullptr, X);
  linear_qkv<<<256, 256, 0, stream>>>(X, wbf + 1 * 65536, wbf + 2 * 65536,
                                      wbf + 3 * 65536, qf16, kf16, vf16);
  pack_kv<<<384, 256, 0, stream>>>(kf16, vf16, kfrag, vfrag);
  fractal_attn<<<1024, 256, 0, stream>>>((const _Float16*)(wbf + 6 * 65536),
                                         qf16, kfrag, vfrag, vsum);
  linear_bf<<<256, 256, 0, stream>>>(vsum, wbf + 4 * 65536, vsum, X, Y);
  linear_bf<<<256, 256, 0, stream>>>(Y, wbf + 5 * 65536, nullptr, nullptr, out);
}

// Round 8
// 123.748 us; speedup vs baseline: 2.2092x; 2.2092x over previous
//
#include <hip/hip_runtime.h>
#include <hip/hip_bf16.h>

// FractalTransformer fused kernels, round 8.
// vs r6 (102us attn): keep r6's register footprint EXACTLY (no acc/vq
// doubling -- r4/r7 proved M_wave=64 leaves no room for a 2-deep pipe),
// add register-free schedule fixes: (1) 4-wave blocks + raw s_barrier per
// tile (no LDS -> no vmcnt drain) so co-resident waves stay on the same
// k/v tile -> L1 serves ~3/4 of the shared k-stream; (2) T14 reorder:
// LOADK(t+1) after the MFMA cluster (bf regs dead, reload in place, k
// latency hides under UPDATE), LOADV(t+1) after UPDATE (v latency hides
// under barrier + next MFMA). Tripwire: FETCH_SIZE >> 4MB means spill.

typedef __attribute__((ext_vector_type(8))) short short8;
typedef __attribute__((ext_vector_type(4))) float f32x4;
typedef __attribute__((ext_vector_type(8))) _Float16 half8;
typedef __attribute__((ext_vector_type(4))) _Float16 half4;

#define DD 256
#define SS 512
#define LOG2E 1.4426950408889634f
#define LN2   0.6931471805599453f

__device__ __forceinline__ unsigned short f2bf(float f) {
  unsigned int b = __float_as_uint(f);
  b += 0x7FFFu + ((b >> 16) & 1u);   // RNE
  return (unsigned short)(b >> 16);
}
__device__ __forceinline__ short8 cvt8(f32x4 lo, f32x4 hi) {
  short8 r;
  r[0]=(short)f2bf(lo[0]); r[1]=(short)f2bf(lo[1]);
  r[2]=(short)f2bf(lo[2]); r[3]=(short)f2bf(lo[3]);
  r[4]=(short)f2bf(hi[0]); r[5]=(short)f2bf(hi[1]);
  r[6]=(short)f2bf(hi[2]); r[7]=(short)f2bf(hi[3]);
  return r;
}

// ------------------------------------------------------------------
// One-time: bf16-convert 6 weights; (w_al + I) -> f16. out = 7 x [256][256].
// ------------------------------------------------------------------
__global__ __launch_bounds__(256) void prep_weights(
    const float* __restrict__ w0, const float* __restrict__ w1,
    const float* __restrict__ w2, const float* __restrict__ w3,
    const float* __restrict__ w4, const float* __restrict__ w5,
    const float* __restrict__ wal, unsigned short* __restrict__ out)
{
  const int bi = blockIdx.x;               // 7*32
  const int m = bi >> 5;
  const int off = ((bi & 31) * 256 + threadIdx.x) * 8;
  const float* src = m==0?w0: m==1?w1: m==2?w2: m==3?w3: m==4?w4: m==5?w5: wal;
  f32x4 a = *(const f32x4*)(src + off);
  f32x4 b = *(const f32x4*)(src + off + 4);
  if (m == 6) {                            // fold residual (+I), store f16
    const int e = off >> 8, d = off & 255;
#pragma unroll
    for (int jj = 0; jj < 4; ++jj) {
      if (e == d + jj)     a[jj] += 1.0f;
      if (e == d + 4 + jj) b[jj] += 1.0f;
    }
    half8 h;
#pragma unroll
    for (int jj = 0; jj < 4; ++jj) {
      h[jj]     = (_Float16)a[jj];
      h[jj + 4] = (_Float16)b[jj];
    }
    *(half8*)(out + (size_t)m * 65536 + off) = h;
  } else {
    *(short8*)(out + (size_t)m * 65536 + off) = cvt8(a, b);
  }
}

// ------------------------------------------------------------------
// out[1024,256] = A @ Wbf^T (+res1)(+res2). grid 256 = 64 rowblk x 4 colblk.
// ------------------------------------------------------------------
__global__ __launch_bounds__(256) void linear_bf(
    const float* __restrict__ A, const unsigned short* __restrict__ Wbf,
    const float* __restrict__ res1, const float* __restrict__ res2,
    float* __restrict__ out)
{
  const int bi = blockIdx.x;
  const int rb = (bi >> 2) * 16;
  const int cb = (bi & 3) * 64;
  const int tid = threadIdx.x;
  const int wv = tid >> 6, lane = tid & 63;
  const int g = lane >> 4, c = lane & 15;
  const int arow = rb + c;
  const int wrow = cb + wv * 16 + c;

  f32x4 acc = (f32x4){0.f, 0.f, 0.f, 0.f};
#pragma unroll
  for (int ks = 0; ks < 8; ++ks) {
    const int d0 = ks * 32 + g * 8;
    f32x4 a0 = *(const f32x4*)(A + arow * DD + d0);
    f32x4 a1 = *(const f32x4*)(A + arow * DD + d0 + 4);
    short8 av = cvt8(a0, a1);
    short8 bv = *(const short8*)(Wbf + wrow * DD + d0);
    acc = __builtin_amdgcn_mfma_f32_16x16x32_bf16(av, bv, acc, 0, 0, 0);
  }
#pragma unroll
  for (int j = 0; j < 4; ++j) {
    const int ro = rb + g * 4 + j;
    const int co = cb + wv * 16 + c;
    float v = acc[j];
    if (res1) v += res1[ro * DD + co];
    if (res2) v += res2[ro * DD + co];
    out[ro * DD + co] = v;
  }
}

// ------------------------------------------------------------------
// q = f16((X + X@Wq^T)*log2e);  k,v = f16(X + X@{Wk,Wv}^T)
// ------------------------------------------------------------------
__global__ __launch_bounds__(256) void linear_qkv(
    const float* __restrict__ X,
    const unsigned short* __restrict__ Wq, const unsigned short* __restrict__ Wk,
    const unsigned short* __restrict__ Wv,
    _Float16* __restrict__ qout, _Float16* __restrict__ kout,
    _Float16* __restrict__ vout)
{
  const int bi = blockIdx.x;
  const int rb = (bi >> 2) * 16;
  const int cb = (bi & 3) * 64;
  const int tid = threadIdx.x;
  const int wv = tid >> 6, lane = tid & 63;
  const int g = lane >> 4, c = lane & 15;
  const int arow = rb + c;
  const int wrow = cb + wv * 16 + c;

  f32x4 aq = (f32x4){0.f,0.f,0.f,0.f};
  f32x4 ak = (f32x4){0.f,0.f,0.f,0.f};
  f32x4 av_ = (f32x4){0.f,0.f,0.f,0.f};
#pragma unroll
  for (int ks = 0; ks < 8; ++ks) {
    const int d0 = ks * 32 + g * 8;
    f32x4 a0 = *(const f32x4*)(X + arow * DD + d0);
    f32x4 a1 = *(const f32x4*)(X + arow * DD + d0 + 4);
    short8 af = cvt8(a0, a1);
    short8 bq = *(const short8*)(Wq + wrow * DD + d0);
    aq = __builtin_amdgcn_mfma_f32_16x16x32_bf16(af, bq, aq, 0, 0, 0);
    short8 bk = *(const short8*)(Wk + wrow * DD + d0);
    ak = __builtin_amdgcn_mfma_f32_16x16x32_bf16(af, bk, ak, 0, 0, 0);
    short8 bv = *(const short8*)(Wv + wrow * DD + d0);
    av_ = __builtin_amdgcn_mfma_f32_16x16x32_bf16(af, bv, av_, 0, 0, 0);
  }
#pragma unroll
  for (int j = 0; j < 4; ++j) {
    const int ro = rb + g * 4 + j;
    const int co = cb + wv * 16 + c;
    const float base = X[ro * DD + co];
    qout[ro * DD + co] = (_Float16)((base + aq[j]) * LOG2E);
    kout[ro * DD + co] = (_Float16)(base + ak[j]);
    vout[ro * DD + co] = (_Float16)(base + av_[j]);
  }
}

// ------------------------------------------------------------------
// Pack k,v (f16, [b][s][d]) into MFMA-fragment order.
// k: ids [0, 32768): id = b*16384 + t2*512 + ks*64 + lane -> 8 f16:
//   k[b][t2*16 + (lane&15)][ks*32 + (lane>>4)*8 + 0..7]
// v: ids [32768, 98304): id2 = b*32768 + t2*1024 + wv*256 + i*64 + lane
//   -> 4 f16: v[b][t2*16 + (lane&15)][wv*64 + i*16 + (lane>>4)*4 + 0..3]
// ------------------------------------------------------------------
__global__ __launch_bounds__(256) void pack_kv(
    const _Float16* __restrict__ k, const _Float16* __restrict__ v,
    _Float16* __restrict__ kfrag, _Float16* __restrict__ vfrag)
{
  const int id = blockIdx.x * 256 + threadIdx.x;   // 98304
  if (id < 32768) {
    const int lane = id & 63, ks = (id >> 6) & 7, t2 = (id >> 9) & 31, b = id >> 14;
    const int g = lane >> 4, c = lane & 15;
    const _Float16* src = k + ((size_t)(b * SS + t2 * 16 + c) * DD + ks * 32 + g * 8);
    *(half8*)(kfrag + (size_t)id * 8) = *(const half8*)src;
  } else {
    const int id2 = id - 32768;                    // 0..65535
    const int lane = id2 & 63, i = (id2 >> 6) & 3, wv = (id2 >> 8) & 3,
              t2 = (id2 >> 10) & 31, b = id2 >> 15;
    const int g = lane >> 4, c = lane & 15;
    const _Float16* src = v + ((size_t)(b * SS + t2 * 16 + c) * DD + wv * 64 + i * 16 + g * 4);
    *(half4*)(vfrag + (size_t)id2 * 4) = *(const half4*)src;
  }
}

// ------------------------------------------------------------------
// Fused fractal attention v8. Grid 1024 = b x sq; 4 waves (256 thr).
// Wave wv owns e in [wv*64, +64); all 4 waves stream the SAME kfrag
// sequence, kept aligned by a raw s_barrier per tile (no LDS -> cheap).
// T14 reorder: LOADK(t+1) after MFMA (k latency under UPDATE),
// LOADV(t+1) after UPDATE (v latency under barrier + next MFMA).
// ------------------------------------------------------------------
__global__ __launch_bounds__(256, 2) void fractal_attn(
    const _Float16* __restrict__ walI,   // f16 (wal+I), [256][256]
    const _Float16* __restrict__ qf,     // f16, pre-scaled by log2e
    const _Float16* __restrict__ kfrag,
    const _Float16* __restrict__ vfrag,
    float* __restrict__ vsum)
{
  const int bid = blockIdx.x;            // 1024
  const int sq = bid & 511;
  const int b  = bid >> 9;
  const int tid = threadIdx.x;
  const int wv = tid >> 6;
  const int lane = tid & 63;
  const int g = lane >> 4, c = lane & 15;

  // ---- A' fragments: wave owns e in [wv*64, wv*64+64) ----
  half8 afrag[4][8];
  {
    const _Float16* qrow = qf + (size_t)(b * SS + sq) * DD;
    half8 q8[8];
#pragma unroll
    for (int ks = 0; ks < 8; ++ks)
      q8[ks] = *(const half8*)(qrow + ks * 32 + g * 8);
#pragma unroll
    for (int i = 0; i < 4; ++i) {
      const int e = wv * 64 + i * 16 + c;
      const _Float16* wrow = walI + (size_t)e * DD;
#pragma unroll
      for (int ks = 0; ks < 8; ++ks)
        afrag[i][ks] = (*(const half8*)(wrow + ks * 32 + g * 8)) * q8[ks];
    }
  }

  // ---- fragment stream bases ----
  const _Float16* kfb = kfrag + (size_t)b * 131072 + lane * 8;   // + t2*4096 + ks*512
  const _Float16* vfb = vfrag + (size_t)b * 131072 + wv * 1024 + lane * 4;  // + t2*4096 + i*256

  // ---- state: 16 e-slots per lane (e = wv*64 + i*16 + g*4 + j) ----
  float mst[16], sst[16], vst[16];
#pragma unroll
  for (int s = 0; s < 16; ++s) { mst[s] = -1e30f; sst[s] = 0.f; vst[s] = 0.f; }

  half8 bf[8];
  half4 vq[4];
  f32x4 acc[4];
  const f32x4 zeroc = (f32x4){0.f, 0.f, 0.f, 0.f};

  // ---- prologue: tile 0 loads ----
#pragma unroll
  for (int ks = 0; ks < 8; ++ks) bf[ks] = *(const half8*)(kfb + ks * 512);
#pragma unroll
  for (int i = 0; i < 4; ++i) vq[i] = *(const half4*)(vfb + i * 256);

#pragma unroll 1
  for (int t2 = 0; t2 < 32; ++t2) {
    __builtin_amdgcn_s_barrier();        // align waves on the shared tile

    // ---- MFMA cluster (32 MFMAs, 4 independent acc chains) ----
    __builtin_amdgcn_s_setprio(1);
#pragma unroll
    for (int i = 0; i < 4; ++i)
      acc[i] = __builtin_amdgcn_mfma_f32_16x16x32_f16(afrag[i][0], bf[0], zeroc, 0, 0, 0);
#pragma unroll
    for (int ks = 1; ks < 8; ++ks)
#pragma unroll
      for (int i = 0; i < 4; ++i)
        acc[i] = __builtin_amdgcn_mfma_f32_16x16x32_f16(afrag[i][ks], bf[ks], acc[i], 0, 0, 0);
    __builtin_amdgcn_s_setprio(0);

    // ---- prefetch next k tile in place (bf dead after MFMA issue) ----
    if (t2 < 31) {
      const _Float16* kf_ = kfb + (t2 + 1) * 4096;
#pragma unroll
      for (int ks = 0; ks < 8; ++ks) bf[ks] = *(const half8*)(kf_ + ks * 512);
    }

    // ---- online update: slot s = i*4+j; sk = t2*16 + c ----
#pragma unroll
    for (int i = 0; i < 4; ++i) {
#pragma unroll
      for (int j = 0; j < 4; ++j) {
        const int s = i * 4 + j;
        const float L = acc[i][j];
        mst[s] = fmaxf(mst[s], L);
        const float p = L * __builtin_amdgcn_exp2f(L);
        sst[s] += fabsf(p);
        vst[s] = fmaf((float)vq[i][j], p, vst[s]);
      }
    }

    // ---- prefetch next v tile (vq dead after update) ----
    if (t2 < 31) {
      const _Float16* vf_ = vfb + (t2 + 1) * 4096;
#pragma unroll
      for (int i = 0; i < 4; ++i) vq[i] = *(const half4*)(vf_ + i * 256);
    }
  }

  // ---- merge across the 16 sk-lanes (same g => same e) ----
#pragma unroll
  for (int mask = 1; mask <= 8; mask <<= 1) {
#pragma unroll
    for (int s = 0; s < 16; ++s) {
      mst[s] = fmaxf(mst[s], __shfl_xor(mst[s], mask));
      sst[s] += __shfl_xor(sst[s], mask);
      vst[s] += __shfl_xor(vst[s], mask);
    }
  }

  if (c == 0) {
    float* orow = vsum + (size_t)(b * SS + sq) * DD;
#pragma unroll
    for (int i = 0; i < 4; ++i) {
      f32x4 o;
#pragma unroll
      for (int j = 0; j < 4; ++j) {
        const int s = i * 4 + j;
        const float tt = LN2 * __builtin_amdgcn_exp2f(-mst[s]);
        o[j] = vst[s] * tt / (sst[s] * tt + 1.0f);
      }
      *(f32x4*)(orow + wv * 64 + i * 16 + g * 4) = o;
    }
  }
}

// ------------------------------------------------------------------
extern "C" void kernel_launch(void* const* d_in, const int* in_sizes, int n_in,
                              void* d_out, int out_size, void* d_ws, size_t ws_size,
                              hipStream_t stream) {
  const float* x     = (const float*)d_in[0];
  const float* w_pre = (const float*)d_in[1];
  const float* w_q   = (const float*)d_in[2];
  const float* w_k   = (const float*)d_in[3];
  const float* w_va  = (const float*)d_in[4];
  const float* w_al  = (const float*)d_in[5];
  const float* w_vo  = (const float*)d_in[6];
  const float* w_end = (const float*)d_in[7];
  float* out = (float*)d_out;

  char* ws = (char*)d_ws;
  float*    X     = (float*)(ws);                         // 1MB
  float*    Y     = (float*)(ws + (1 << 20));             // 1MB
  float*    vsum  = (float*)(ws + (2 << 20));             // 1MB
  _Float16* qf16  = (_Float16*)(ws + (3 << 20));          // 512KB
  _Float16* kf16  = (_Float16*)(ws + (3 << 20) + (512 << 10));
  _Float16* vf16  = (_Float16*)(ws + (4 << 20));
  _Float16* kfrag = (_Float16*)(ws + (4 << 20) + (512 << 10));  // 512KB
  _Float16* vfrag = (_Float16*)(ws + (5 << 20));                // 512KB
  unsigned short* wbf = (unsigned short*)(ws + (5 << 20) + (512 << 10));
  // wbf order: pre, q, k, va, vo, end, walI(+I, f16)

  prep_weights<<<224, 256, 0, stream>>>(w_pre, w_q, w_k, w_va, w_vo, w_end,
                                        w_al, wbf);
  linear_bf<<<256, 256, 0, stream>>>(x, wbf + 0 * 65536, nullptr, nullptr, X);
  linear_qkv<<<256, 256, 0, stream>>>(X, wbf + 1 * 65536, wbf + 2 * 65536,
                                      wbf + 3 * 65536, qf16, kf16, vf16);
  pack_kv<<<384, 256, 0, stream>>>(kf16, vf16, kfrag, vfrag);
  fractal_attn<<<1024, 256, 0, stream>>>((const _Float16*)(wbf + 6 * 65536),
                                         qf16, kfrag, vfrag, vsum);
  linear_bf<<<256, 256, 0, stream>>>(vsum, wbf + 4 * 65536, vsum, X, Y);
  linear_bf<<<256, 256, 0, stream>>>(Y, wbf + 5 * 65536, nullptr, nullptr, out);
}